// Round 1
// 142.352 us; speedup vs baseline: 1.0379x; 1.0379x over previous
//
#include <hip/hip_runtime.h>
#include <hip/hip_bf16.h>
#include <stdint.h>

typedef unsigned short u16;
typedef __bf16 bf16;
typedef __bf16 bf16x8 __attribute__((ext_vector_type(8)));
typedef float f32x4 __attribute__((ext_vector_type(4)));
typedef float f32x16 __attribute__((ext_vector_type(16)));

#define NSEQ 2048
#define NDH 64
#define NH 8
#define QKS 2097152ull  // elements per q/k/v/t plane

__device__ __forceinline__ float b2f(u16 u) {
  union { float f; uint32_t i; } x; x.i = ((uint32_t)u) << 16; return x.f;
}
__device__ __forceinline__ u16 f2b(float f) {
  union { float f; uint32_t i; } x; x.f = f;
  const uint32_t r = x.i + 0x7FFFu + ((x.i >> 16) & 1u);
  return (u16)(r >> 16);
}
// packed f32x2 -> bf16x2 (RNE, v_cvt_pk path)
__device__ __forceinline__ uint32_t b2pk(float a, float b) {
  union { __hip_bfloat162 h; uint32_t u; } x;
  x.h = __float22bfloat162_rn(make_float2(a, b));
  return x.u;
}
// async global->LDS, 16B per lane. lds ptr must be wave-uniform base;
// HW writes base + lane*16. size is a literal (required).
__device__ __forceinline__ void gl16(const void* g, void* l) {
  __builtin_amdgcn_global_load_lds(
      (const __attribute__((address_space(1))) void*)g,
      (__attribute__((address_space(3))) void*)l, 16, 0, 0);
}

// ---------------------------------------------------------------------------
// K0: one-shot f32 -> bf16 conversion of X, Wqkv, Wout (RNE packed converts,
// identical rounding to the old in-staging b2pk, so GEMM inputs are
// bit-identical). Memory-bound: ~14.7MB read + ~7.3MB write.
// Blocks: [0,1024) X (2M elem), [1024,1536) Wqkv (1M), [1536,1792) Wout (512K)
// ---------------------------------------------------------------------------
__global__ __launch_bounds__(256) void k_cvt(
    const float* __restrict__ X, const float* __restrict__ Wq,
    const float* __restrict__ Wo, u16* __restrict__ Xb,
    u16* __restrict__ Wqb, u16* __restrict__ Wob) {
  const int b = blockIdx.x;
  const float* src; u16* dst; int idx;
  if (b < 1024)      { src = X;  dst = Xb;  idx = b; }
  else if (b < 1536) { src = Wq; dst = Wqb; idx = b - 1024; }
  else               { src = Wo; dst = Wob; idx = b - 1536; }
  const size_t off = ((size_t)idx * 256 + threadIdx.x) * 8;
  const float4 a = *(const float4*)(src + off);
  const float4 c = *(const float4*)(src + off + 4);
  uint4 o = {b2pk(a.x, a.y), b2pk(a.z, a.w), b2pk(c.x, c.y), b2pk(c.z, c.w)};
  *(uint4*)(dst + off) = o;
}

// ---------------------------------------------------------------------------
// K1: qkvt = Xb[4096,512](bf16) @ Wb[2048,512](bf16)^T (MFMA 16x16x32),
// m97 structure: 128x128 tile, BK=32, global_load_lds width-16 staging into
// linear [rows][32] LDS, 2 barriers per K-step. q plane pre-scaled by
// dh^-0.5*log2(e). V plane stored transposed [b,h,dim,tok]. LDS-transpose
// epilogue -> coalesced uint4 stores.
// ---------------------------------------------------------------------------
__global__ __launch_bounds__(256) void k_gemm_qkvt(
    const u16* __restrict__ Xb, const u16* __restrict__ Wb, u16* __restrict__ qkvt) {
  __shared__ __align__(16) bf16 smem[18432];  // stage As[128][32]|Bs[128][32]=16KB | epi 4x(64x72)
  bf16* As = smem;          // [128][32]
  bf16* Bs = smem + 4096;   // [128][32]
  const int tid = threadIdx.x;
  const int n0 = blockIdx.x * 128;
  const int m0 = blockIdx.y * 128;
  const int w = tid >> 6, lane = tid & 63;
  const int wy = w >> 1, wx = w & 1;
  const int quad = lane >> 4, l15 = lane & 15;
  const int srow = tid >> 2, sc8 = (tid & 3) * 8;  // 4 lanes/row, 8 elem (16B) each
  const u16* ag = Xb + (size_t)(m0 + srow) * 512 + sc8;
  const u16* bg = Wb + (size_t)(n0 + srow) * 512 + sc8;
  // wave-uniform LDS dests: issue0 rows 0..63 (bytes [0,4096)), issue1 rows 64..127
  char* aL0 = (char*)As + w * 1024;
  char* aL1 = (char*)As + 4096 + w * 1024;
  char* bL0 = (char*)Bs + w * 1024;
  char* bL1 = (char*)Bs + 4096 + w * 1024;
  f32x4 acc[4][4];
#pragma unroll
  for (int mt = 0; mt < 4; ++mt)
#pragma unroll
    for (int nt = 0; nt < 4; ++nt) acc[mt][nt] = (f32x4){0.f, 0.f, 0.f, 0.f};
  for (int kc = 0; kc < 512; kc += 32) {
    __syncthreads();
    gl16(ag + kc,            aL0);
    gl16(ag + kc + 64 * 512, aL1);
    gl16(bg + kc,            bL0);
    gl16(bg + kc + 64 * 512, bL1);
    __syncthreads();   // compiler drains vmcnt(0) here
    bf16x8 afr[4], bfr[4];
#pragma unroll
    for (int mt = 0; mt < 4; ++mt)
      afr[mt] = *(const bf16x8*)&As[(wy * 64 + mt * 16 + l15) * 32 + quad * 8];
#pragma unroll
    for (int nt = 0; nt < 4; ++nt)
      bfr[nt] = *(const bf16x8*)&Bs[(wx * 64 + nt * 16 + l15) * 32 + quad * 8];
#pragma unroll
    for (int mt = 0; mt < 4; ++mt)
#pragma unroll
      for (int nt = 0; nt < 4; ++nt)
        acc[mt][nt] = __builtin_amdgcn_mfma_f32_16x16x32_bf16(afr[mt], bfr[nt], acc[mt][nt], 0, 0, 0);
  }
  __syncthreads();   // staging reads done; reuse smem for epilogue
  const int cbase = n0 + wx * 64;
  const int which = cbase >> 9;       // 0=q 1=k 2=v 3=t
  const int h     = (cbase >> 6) & 7;
  // q scale: dh^-0.5 * log2(e) so attention exp is raw exp2
  const float scale = (which == 0) ? 0.18033688011112043f : 1.0f;
  bf16* Cw = smem + w * 4608;         // per-wave [64][72]
  if (which == 2) {
#pragma unroll
    for (int nt = 0; nt < 4; ++nt)
#pragma unroll
      for (int mt = 0; mt < 4; ++mt)
#pragma unroll
        for (int r = 0; r < 4; ++r)
          Cw[(nt * 16 + l15) * 72 + mt * 16 + quad * 4 + r] = (bf16)acc[mt][nt][r];
  } else {
#pragma unroll
    for (int mt = 0; mt < 4; ++mt)
#pragma unroll
      for (int nt = 0; nt < 4; ++nt)
#pragma unroll
        for (int r = 0; r < 4; ++r)
          Cw[(mt * 16 + quad * 4 + r) * 72 + nt * 16 + l15] = (bf16)(acc[mt][nt][r] * scale);
  }
  const int mb = m0 + wy * 64;
  const int bb = mb >> 11;
  const int nn0 = mb & (NSEQ - 1);
  if (which == 2) {
    u16* vt = qkvt + 2ull * QKS + (size_t)(bb * NH + h) * NDH * NSEQ;
#pragma unroll
    for (int p = 0; p < 8; ++p) {
      const int d = p * 8 + (lane >> 3);
      const int t8 = (lane & 7) * 8;
      const uint4 v = *(const uint4*)&Cw[d * 72 + t8];
      *(uint4*)(vt + (size_t)d * NSEQ + nn0 + t8) = v;
    }
  } else {
    u16* dst = qkvt + (size_t)which * QKS + ((size_t)(bb * NH + h) * NSEQ + nn0) * NDH;
#pragma unroll
    for (int p = 0; p < 8; ++p) {
      const int tok = p * 8 + (lane >> 3);
      const int c8 = (lane & 7) * 8;
      const uint4 v = *(const uint4*)&Cw[tok * 72 + c8];
      *(uint4*)(dst + (size_t)tok * NDH + c8) = v;
    }
  }
}

// ---------------------------------------------------------------------------
// K2: MFMA flash attention, 32x32x16 key-split design. (unchanged)
// ---------------------------------------------------------------------------
__global__ __launch_bounds__(256) void k_attn(
    const u16* __restrict__ qkvt, u16* __restrict__ out12) {
  __shared__ __align__(16) bf16 Qs[64 * 72];
  __shared__ __align__(16) bf16 KV[2 * 64 * 72];   // Ks | Vt ; epilogue: Osum f32[2][32][64]
  __shared__ __align__(16) bf16 Pw[4 * 32 * 72];   // per-wave [32 q][72]
  __shared__ float Lpart[4][32];
  bf16* Ks = KV;
  bf16* Vt = KV + 64 * 72;
  const int tid = threadIdx.x;
  const int bh  = blockIdx.x;
  const int q0  = blockIdx.y * 64;
  const size_t base  = (size_t)bh * (NSEQ * NDH);
  const size_t vbase = 2ull * QKS + (size_t)bh * (NDH * NSEQ);
  const int wq = tid >> 6, lane = tid & 63;
  const int qh = wq >> 1, kh = wq & 1;
  const int l31 = lane & 31, hi = lane >> 5;
  const int srow = tid >> 2, sc0 = (tid & 3) * 16;
  { // stage 64 Q rows [token][dim]
    const u16* qp = qkvt + base + (size_t)(q0 + srow) * NDH + sc0;
    *(uint4*)&Qs[srow * 72 + sc0]     = *(const uint4*)qp;
    *(uint4*)&Qs[srow * 72 + sc0 + 8] = *(const uint4*)(qp + 8);
  }
  __syncthreads();
  // Q B-frags (loop-invariant): B[n=q=l31][k=dim chunk]
  bf16x8 qb[4];
#pragma unroll
  for (int c = 0; c < 4; ++c)
    qb[c] = *(const bf16x8*)&Qs[(qh * 32 + l31) * 72 + c * 16 + hi * 8];
  float lacc = 0.f;
  f32x16 o[2];
#pragma unroll
  for (int nt = 0; nt < 2; ++nt)
#pragma unroll
    for (int r = 0; r < 16; ++r) o[nt][r] = 0.f;
  const u16* kp = qkvt + QKS + base + (size_t)srow * NDH + sc0;
  const u16* vp = qkvt + vbase + (size_t)srow * NSEQ + sc0;
  uint4 k0 = *(const uint4*)kp;
  uint4 k1 = *(const uint4*)(kp + 8);
  uint4 v0 = *(const uint4*)vp;
  uint4 v1 = *(const uint4*)(vp + 8);
  for (int kt = 0; kt < 32; ++kt) {
    __syncthreads();
    *(uint4*)&Ks[srow * 72 + sc0]     = k0;
    *(uint4*)&Ks[srow * 72 + sc0 + 8] = k1;
    *(uint4*)&Vt[srow * 72 + sc0]     = v0;
    *(uint4*)&Vt[srow * 72 + sc0 + 8] = v1;
    __syncthreads();
    if (kt < 31) {   // prefetch next tile during compute
      const u16* kn = kp + (size_t)(kt + 1) * 64 * NDH;
      const u16* vn = vp + (kt + 1) * 64;
      k0 = *(const uint4*)kn;
      k1 = *(const uint4*)(kn + 8);
      v0 = *(const uint4*)vn;
      v1 = *(const uint4*)(vn + 8);
    }
    // S^T: D[m=key_loc][n=q], A = K rows (my key half), B = Q (cached)
    f32x16 s;
#pragma unroll
    for (int r = 0; r < 16; ++r) s[r] = 0.f;
#pragma unroll
    for (int c = 0; c < 4; ++c) {
      const bf16x8 ka = *(const bf16x8*)&Ks[(kh * 32 + l31) * 72 + c * 16 + hi * 8];
      s = __builtin_amdgcn_mfma_f32_32x32x16_bf16(ka, qb[c], s, 0, 0, 0);
    }
    // softmax: p = exp2(s); per-query l: in-lane + shfl_xor(32)
    float ts = 0.f;
#pragma unroll
    for (int r = 0; r < 16; ++r) {
      s[r] = __builtin_amdgcn_exp2f(s[r]);
      ts += s[r];
    }
    ts += __shfl_xor(ts, 32);
    lacc += ts;
    // P[q=l31][key_loc]: C rows = keys (r&3)+8*(r>>2)+4*hi -> b64 packs
    bf16* pr = Pw + (wq * 32 + l31) * 72;
#pragma unroll
    for (int g = 0; g < 4; ++g) {
      bf16 pk[4] = {(bf16)s[4 * g], (bf16)s[4 * g + 1],
                    (bf16)s[4 * g + 2], (bf16)s[4 * g + 3]};
      *(uint2*)&pr[g * 8 + hi * 4] = *(const uint2*)pk;
    }
    // PV: A = P[m=q][k=key_loc] (wave-local, no barrier), B = Vt[n=d][k]
#pragma unroll
    for (int c = 0; c < 2; ++c) {
      const bf16x8 pa = *(const bf16x8*)&Pw[(wq * 32 + l31) * 72 + c * 16 + hi * 8];
      const bf16x8 vb0 = *(const bf16x8*)&Vt[l31 * 72 + kh * 32 + c * 16 + hi * 8];
      const bf16x8 vb1 = *(const bf16x8*)&Vt[(32 + l31) * 72 + kh * 32 + c * 16 + hi * 8];
      o[0] = __builtin_amdgcn_mfma_f32_32x32x16_bf16(pa, vb0, o[0], 0, 0, 0);
      o[1] = __builtin_amdgcn_mfma_f32_32x32x16_bf16(pa, vb1, o[1], 0, 0, 0);
    }
  }
  __syncthreads();   // all Vt reads done; overlay Osum on KV
  if (lane < 32) Lpart[wq][lane] = lacc;
  float* Osum = (float*)KV;   // [2][32][64]
  if (kh == 1) {
#pragma unroll
    for (int nt = 0; nt < 2; ++nt)
#pragma unroll
      for (int r = 0; r < 16; ++r) {
        const int row = (r & 3) + 8 * (r >> 2) + 4 * hi;
        Osum[(qh * 32 + row) * 64 + nt * 32 + l31] = o[nt][r];
      }
  }
  __syncthreads();
  if (kh == 0) {
    const int bb = bh >> 3, h = bh & 7;
#pragma unroll
    for (int r = 0; r < 16; ++r) {
      const int row = (r & 3) + 8 * (r >> 2) + 4 * hi;
      const float lt = Lpart[qh * 2][row] + Lpart[qh * 2 + 1][row];
      const float inv = 1.f / lt;
      const int nn = q0 + qh * 32 + row;
      u16* dst = out12 + (size_t)(bb * NSEQ + nn) * 1024 + h * 128;
      dst[l31]      = f2b((o[0][r] + Osum[(qh * 32 + row) * 64 + l31]) * inv);
      dst[32 + l31] = f2b((o[1][r] + Osum[(qh * 32 + row) * 64 + 32 + l31]) * inv);
    }
  }
}

// ---------------------------------------------------------------------------
// K4: positional-decay attention via separable scans (sinv hoisted). (unchanged)
// ---------------------------------------------------------------------------
__global__ __launch_bounds__(256) void k_band(
    const u16* __restrict__ qkvt, u16* __restrict__ out12) {
  __shared__ float sinv[4][192];
  __shared__ float fbuf[4][64][68];
  const int tid = threadIdx.x;
  const int w = tid >> 6, d = tid & 63;
  const int c  = blockIdx.x * 4 + w;       // chunk 0..31
  const int i0 = c * 64;
  const int bh = blockIdx.y;
  const size_t tb = 3ull * QKS + (size_t)bh * (NSEQ * NDH);
  const float EI = 0.36787944117144233f;   // 1/e
  const float RR = 0.69220062755534635f;   // exp(-1/e)
  const float OMR = 1.f - RR;
#pragma unroll
  for (int p = 0; p < 3; ++p) {
    const int j = i0 - 64 + p * 64 + d;
    const float r1 = __expf(-(float)(j + 1) * EI);
    const float r2 = __expf(-(float)(NSEQ - j) * EI);
    sinv[w][p * 64 + d] = OMR / (1.f - r1 + RR - r2);
  }
  const u16* tp = qkvt + tb + d;
  float f = 0.f;
  if (c > 0) {
#pragma unroll 8
    for (int jj = 0; jj < 64; ++jj)
      f = RR * f + sinv[w][jj] * b2f(tp[(size_t)(i0 - 64 + jj) * NDH]);
  }
#pragma unroll 8
  for (int jj = 0; jj < 64; ++jj) {
    f = RR * f + sinv[w][64 + jj] * b2f(tp[(size_t)(i0 + jj) * NDH]);
    fbuf[w][jj][d] = f;
  }
  float b = 0.f;
  if (c < 31) {
#pragma unroll 8
    for (int jj = 63; jj >= 0; --jj)
      b = RR * b + sinv[w][128 + jj] * b2f(tp[(size_t)(i0 + 64 + jj) * NDH]);
  }
  const int bb = bh >> 3, h = bh & 7;
#pragma unroll 8
  for (int jj = 63; jj >= 0; --jj) {
    const float g = sinv[w][64 + jj] * b2f(tp[(size_t)(i0 + jj) * NDH]);
    b = RR * b + g;
    out12[(size_t)(bb * NSEQ + i0 + jj) * 1024 + h * 128 + 64 + d] =
        f2b(fbuf[w][jj][d] + b - g);
  }
}

// ---------------------------------------------------------------------------
// K3: out = out12[4096,1024](bf16) @ Wob[512,1024](bf16)^T + bias -> f32.
// 64x64 tiles, BK=64 via two [64][32] buffers per operand, global_load_lds
// width-16 staging (no reg round-trip, no in-staging cvt). 16 K-iters.
// ---------------------------------------------------------------------------
__global__ __launch_bounds__(256) void k_gemm_out(
    const u16* __restrict__ A, const u16* __restrict__ Wb,
    const float* __restrict__ bias, float* __restrict__ out) {
  __shared__ __align__(16) float smemf[4352];  // stage 16KB | epi 4x(16x68) f32
  bf16* As0 = (bf16*)smemf;          // [64][32]
  bf16* As1 = (bf16*)smemf + 2048;   // [64][32]
  bf16* Bs0 = (bf16*)smemf + 4096;   // [64][32]
  bf16* Bs1 = (bf16*)smemf + 6144;   // [64][32]
  const int tid = threadIdx.x;
  const int n0 = blockIdx.x * 64;
  const int m0 = blockIdx.y * 64;
  const int w = tid >> 6, lane = tid & 63;
  const int quad = lane >> 4, l15 = lane & 15;
  const int srow = tid >> 2, sc8 = (tid & 3) * 8;
  const u16* ap = A  + (size_t)(m0 + srow) * 1024 + sc8;
  const u16* bp = Wb + (size_t)(n0 + srow) * 1024 + sc8;
  char* aL0 = (char*)smemf + w * 1024;
  char* aL1 = (char*)smemf + 4096  + w * 1024;
  char* bL0 = (char*)smemf + 8192  + w * 1024;
  char* bL1 = (char*)smemf + 12288 + w * 1024;
  f32x4 acc[4];
#pragma unroll
  for (int nt = 0; nt < 4; ++nt) acc[nt] = (f32x4){0.f, 0.f, 0.f, 0.f};
  for (int kc = 0; kc < 1024; kc += 64) {
    __syncthreads();
    gl16(ap + kc,      aL0);
    gl16(ap + kc + 32, aL1);
    gl16(bp + kc,      bL0);
    gl16(bp + kc + 32, bL1);
    __syncthreads();
    const int fr = (w * 16 + l15) * 32 + quad * 8;
    const bf16x8 af0 = *(const bf16x8*)&As0[fr];
    const bf16x8 af1 = *(const bf16x8*)&As1[fr];
#pragma unroll
    for (int nt = 0; nt < 4; ++nt) {
      const int br = (nt * 16 + l15) * 32 + quad * 8;
      acc[nt] = __builtin_amdgcn_mfma_f32_16x16x32_bf16(af0, *(const bf16x8*)&Bs0[br], acc[nt], 0, 0, 0);
      acc[nt] = __builtin_amdgcn_mfma_f32_16x16x32_bf16(af1, *(const bf16x8*)&Bs1[br], acc[nt], 0, 0, 0);
    }
  }
  float bias_v[4];
#pragma unroll
  for (int nt = 0; nt < 4; ++nt) bias_v[nt] = bias[n0 + nt * 16 + l15];
  __syncthreads();   // staging reads done; reuse smem
  float* Cw = smemf + w * 1088;   // per-wave [16][68]
#pragma unroll
  for (int nt = 0; nt < 4; ++nt)
#pragma unroll
    for (int r = 0; r < 4; ++r)
      Cw[(quad * 4 + r) * 68 + nt * 16 + l15] = acc[nt][r] + bias_v[nt];
  // wave-local: no barrier
#pragma unroll
  for (int p = 0; p < 4; ++p) {
    const int row = p * 4 + (lane >> 4);
    const int c4  = (lane & 15) * 4;
    const float4 v = *(const float4*)&Cw[row * 68 + c4];
    *(float4*)(out + (size_t)(m0 + w * 16 + row) * 512 + n0 + c4) = v;
  }
}

extern "C" void kernel_launch(void* const* d_in, const int* in_sizes, int n_in,
                              void* d_out, int out_size, void* d_ws, size_t ws_size,
                              hipStream_t stream) {
  (void)in_sizes; (void)n_in; (void)out_size; (void)ws_size;
  const float* x     = (const float*)d_in[0];
  const float* w_qkv = (const float*)d_in[1];
  const float* w_out = (const float*)d_in[2];
  const float* b_out = (const float*)d_in[3];
  float* out = (float*)d_out;
  u16* ws    = (u16*)d_ws;
  u16* qkvt  = ws;                               // [0, 16MB): 4 planes bf16
  u16* out12 = ws + 8ull  * 1024 * 1024;         // [16MB, 24MB)
  u16* Xb    = ws + 12ull * 1024 * 1024;         // [24MB, 28MB): 4096x512 bf16
  u16* Wqb   = ws + 14ull * 1024 * 1024;         // [28MB, 30MB): 2048x512 bf16
  u16* Wob   = ws + 15ull * 1024 * 1024;         // [30MB, 31MB): 512x1024 bf16
  k_cvt      <<<dim3(1792), 256, 0, stream>>>(x, w_qkv, w_out, Xb, Wqb, Wob);
  k_gemm_qkvt<<<dim3(16, 32), 256, 0, stream>>>(Xb, Wqb, qkvt);
  k_attn     <<<dim3(16, 32), 256, 0, stream>>>(qkvt, out12);
  k_band     <<<dim3(8, 16), 256, 0, stream>>>(qkvt, out12);
  k_gemm_out <<<dim3(8, 64), 256, 0, stream>>>(out12, Wob, b_out, out);
}

// Round 2
// 141.311 us; speedup vs baseline: 1.0456x; 1.0074x over previous
//
#include <hip/hip_runtime.h>
#include <hip/hip_bf16.h>
#include <stdint.h>

typedef unsigned short u16;
typedef __bf16 bf16;
typedef __bf16 bf16x8 __attribute__((ext_vector_type(8)));
typedef float f32x4 __attribute__((ext_vector_type(4)));
typedef float f32x16 __attribute__((ext_vector_type(16)));

#define NSEQ 2048
#define NDH 64
#define NH 8
#define QKS 2097152ull  // elements per q/k/v/t plane

__device__ __forceinline__ float b2f(u16 u) {
  union { float f; uint32_t i; } x; x.i = ((uint32_t)u) << 16; return x.f;
}
__device__ __forceinline__ u16 f2b(float f) {
  union { float f; uint32_t i; } x; x.f = f;
  const uint32_t r = x.i + 0x7FFFu + ((x.i >> 16) & 1u);
  return (u16)(r >> 16);
}
// packed f32x2 -> bf16x2 (RNE, v_cvt_pk path)
__device__ __forceinline__ uint32_t b2pk(float a, float b) {
  union { __hip_bfloat162 h; uint32_t u; } x;
  x.h = __float22bfloat162_rn(make_float2(a, b));
  return x.u;
}
// async global->LDS, 16B per lane. lds ptr must be wave-uniform base;
// HW writes base + lane*16. size is a literal (required).
__device__ __forceinline__ void gl16(const void* g, void* l) {
  __builtin_amdgcn_global_load_lds(
      (const __attribute__((address_space(1))) void*)g,
      (__attribute__((address_space(3))) void*)l, 16, 0, 0);
}

// ---------------------------------------------------------------------------
// K0: one-shot f32 -> bf16 conversion of X, Wqkv, Wout (RNE packed converts).
// Blocks: [0,1024) X (2M elem), [1024,1536) Wqkv (1M), [1536,1792) Wout (512K)
// ---------------------------------------------------------------------------
__global__ __launch_bounds__(256) void k_cvt(
    const float* __restrict__ X, const float* __restrict__ Wq,
    const float* __restrict__ Wo, u16* __restrict__ Xb,
    u16* __restrict__ Wqb, u16* __restrict__ Wob) {
  const int b = blockIdx.x;
  const float* src; u16* dst; int idx;
  if (b < 1024)      { src = X;  dst = Xb;  idx = b; }
  else if (b < 1536) { src = Wq; dst = Wqb; idx = b - 1024; }
  else               { src = Wo; dst = Wob; idx = b - 1536; }
  const size_t off = ((size_t)idx * 256 + threadIdx.x) * 8;
  const float4 a = *(const float4*)(src + off);
  const float4 c = *(const float4*)(src + off + 4);
  uint4 o = {b2pk(a.x, a.y), b2pk(a.z, a.w), b2pk(c.x, c.y), b2pk(c.z, c.w)};
  *(uint4*)(dst + off) = o;
}

// ---------------------------------------------------------------------------
// K1: qkvt = Xb[4096,512](bf16) @ Wb[2048,512](bf16)^T (MFMA 16x16x32),
// 128x128 tile, BK=64 via 4x [128][32] linear buffers, global_load_lds
// width-16 staging, 8 barrier-pairs total (was 16 at BK=32).
// Grid (m-tile, n-tile): per-XCD working set = A-stripe 512KB + B 2MB (L2).
// q plane pre-scaled by dh^-0.5*log2(e). V stored transposed [b,h,dim,tok].
// ---------------------------------------------------------------------------
__global__ __launch_bounds__(256) void k_gemm_qkvt(
    const u16* __restrict__ Xb, const u16* __restrict__ Wb, u16* __restrict__ qkvt) {
  __shared__ __align__(16) bf16 smem[18432];  // stage 32KB (4x8KB) | epi 4x(64x72)
  bf16* A0e = smem;           // [128][32] cols kc..kc+31
  bf16* A1e = smem + 4096;    // [128][32] cols kc+32..63
  bf16* B0e = smem + 8192;
  bf16* B1e = smem + 12288;
  const int tid = threadIdx.x;
  const int m0 = blockIdx.x * 128;
  const int n0 = blockIdx.y * 128;
  const int w = tid >> 6, lane = tid & 63;
  const int wy = w >> 1, wx = w & 1;
  const int quad = lane >> 4, l15 = lane & 15;
  const int srow = tid >> 2, sc8 = (tid & 3) * 8;  // 4 lanes/row, 8 elem (16B)
  const u16* ag = Xb + (size_t)(m0 + srow) * 512 + sc8;
  const u16* bg = Wb + (size_t)(n0 + srow) * 512 + sc8;
  // wave-uniform LDS dests (bytes). Wave w stages rows w*16..w*16+15 (+64).
  char* aL00 = (char*)smem + w * 1024;            // A0 rows 0-63
  char* aL01 = (char*)smem + 4096  + w * 1024;    // A0 rows 64-127
  char* aL10 = (char*)smem + 8192  + w * 1024;    // A1 rows 0-63
  char* aL11 = (char*)smem + 12288 + w * 1024;    // A1 rows 64-127
  char* bL00 = (char*)smem + 16384 + w * 1024;
  char* bL01 = (char*)smem + 20480 + w * 1024;
  char* bL10 = (char*)smem + 24576 + w * 1024;
  char* bL11 = (char*)smem + 28672 + w * 1024;
  f32x4 acc[4][4];
#pragma unroll
  for (int mt = 0; mt < 4; ++mt)
#pragma unroll
    for (int nt = 0; nt < 4; ++nt) acc[mt][nt] = (f32x4){0.f, 0.f, 0.f, 0.f};
  for (int kc = 0; kc < 512; kc += 64) {
    __syncthreads();
    gl16(ag + kc,                 aL00);
    gl16(ag + kc + 64 * 512,      aL01);
    gl16(ag + kc + 32,            aL10);
    gl16(ag + kc + 32 + 64 * 512, aL11);
    gl16(bg + kc,                 bL00);
    gl16(bg + kc + 64 * 512,      bL01);
    gl16(bg + kc + 32,            bL10);
    gl16(bg + kc + 32 + 64 * 512, bL11);
    __syncthreads();   // drain (compiler emits vmcnt(0))
#pragma unroll
    for (int ks = 0; ks < 2; ++ks) {
      const bf16* Ae = ks ? A1e : A0e;
      const bf16* Be = ks ? B1e : B0e;
      bf16x8 afr[4], bfr[4];
#pragma unroll
      for (int mt = 0; mt < 4; ++mt)
        afr[mt] = *(const bf16x8*)&Ae[(wy * 64 + mt * 16 + l15) * 32 + quad * 8];
#pragma unroll
      for (int nt = 0; nt < 4; ++nt)
        bfr[nt] = *(const bf16x8*)&Be[(wx * 64 + nt * 16 + l15) * 32 + quad * 8];
#pragma unroll
      for (int mt = 0; mt < 4; ++mt)
#pragma unroll
        for (int nt = 0; nt < 4; ++nt)
          acc[mt][nt] = __builtin_amdgcn_mfma_f32_16x16x32_bf16(afr[mt], bfr[nt], acc[mt][nt], 0, 0, 0);
    }
  }
  __syncthreads();   // staging reads done; reuse smem for epilogue
  const int cbase = n0 + wx * 64;
  const int which = cbase >> 9;       // 0=q 1=k 2=v 3=t
  const int h     = (cbase >> 6) & 7;
  // q scale: dh^-0.5 * log2(e) so attention exp is raw exp2
  const float scale = (which == 0) ? 0.18033688011112043f : 1.0f;
  bf16* Cw = smem + w * 4608;         // per-wave [64][72]
  if (which == 2) {
#pragma unroll
    for (int nt = 0; nt < 4; ++nt)
#pragma unroll
      for (int mt = 0; mt < 4; ++mt)
#pragma unroll
        for (int r = 0; r < 4; ++r)
          Cw[(nt * 16 + l15) * 72 + mt * 16 + quad * 4 + r] = (bf16)acc[mt][nt][r];
  } else {
#pragma unroll
    for (int mt = 0; mt < 4; ++mt)
#pragma unroll
      for (int nt = 0; nt < 4; ++nt)
#pragma unroll
        for (int r = 0; r < 4; ++r)
          Cw[(mt * 16 + quad * 4 + r) * 72 + nt * 16 + l15] = (bf16)(acc[mt][nt][r] * scale);
  }
  const int mb = m0 + wy * 64;
  const int bb = mb >> 11;
  const int nn0 = mb & (NSEQ - 1);
  if (which == 2) {
    u16* vt = qkvt + 2ull * QKS + (size_t)(bb * NH + h) * NDH * NSEQ;
#pragma unroll
    for (int p = 0; p < 8; ++p) {
      const int d = p * 8 + (lane >> 3);
      const int t8 = (lane & 7) * 8;
      const uint4 v = *(const uint4*)&Cw[d * 72 + t8];
      *(uint4*)(vt + (size_t)d * NSEQ + nn0 + t8) = v;
    }
  } else {
    u16* dst = qkvt + (size_t)which * QKS + ((size_t)(bb * NH + h) * NSEQ + nn0) * NDH;
#pragma unroll
    for (int p = 0; p < 8; ++p) {
      const int tok = p * 8 + (lane >> 3);
      const int c8 = (lane & 7) * 8;
      const uint4 v = *(const uint4*)&Cw[tok * 72 + c8];
      *(uint4*)(dst + (size_t)tok * NDH + c8) = v;
    }
  }
}

// ---------------------------------------------------------------------------
// K2+K4 merged: blocks [0,512) = MFMA flash attention (32x32x16 key-split),
// blocks [512,640) = positional-decay attention via separable scans.
// Union LDS 72.7KB -> 2 blocks/CU either way (attn occupancy unchanged).
// Saves one launch + overlaps band with attn tail. bh = bid&15 keeps the
// 2-heads-per-XCD K/V L2 locality.
// ---------------------------------------------------------------------------
__global__ __launch_bounds__(256) void k_attn_band(
    const u16* __restrict__ qkvt, u16* __restrict__ out12) {
  __shared__ __align__(16) char usmem[72704];
  const int tid = threadIdx.x;
  const int bid = blockIdx.x;
  if (bid < 512) {
    // ---- attention ----
    bf16* Qs = (bf16*)usmem;            // [64][72]
    bf16* KV = Qs + 4608;               // Ks | Vt ; epilogue: Osum f32[2][32][64]
    bf16* Pw = KV + 9216;               // per-wave [32 q][72]
    float* Lpart = (float*)(usmem + 46080);  // [4][32]
    bf16* Ks = KV;
    bf16* Vt = KV + 64 * 72;
    const int bh  = bid & 15;
    const int q0  = (bid >> 4) * 64;
    const size_t base  = (size_t)bh * (NSEQ * NDH);
    const size_t vbase = 2ull * QKS + (size_t)bh * (NDH * NSEQ);
    const int wq = tid >> 6, lane = tid & 63;
    const int qh = wq >> 1, kh = wq & 1;
    const int l31 = lane & 31, hi = lane >> 5;
    const int srow = tid >> 2, sc0 = (tid & 3) * 16;
    { // stage 64 Q rows [token][dim]
      const u16* qp = qkvt + base + (size_t)(q0 + srow) * NDH + sc0;
      *(uint4*)&Qs[srow * 72 + sc0]     = *(const uint4*)qp;
      *(uint4*)&Qs[srow * 72 + sc0 + 8] = *(const uint4*)(qp + 8);
    }
    __syncthreads();
    // Q B-frags (loop-invariant): B[n=q=l31][k=dim chunk]
    bf16x8 qb[4];
#pragma unroll
    for (int c = 0; c < 4; ++c)
      qb[c] = *(const bf16x8*)&Qs[(qh * 32 + l31) * 72 + c * 16 + hi * 8];
    float lacc = 0.f;
    f32x16 o[2];
#pragma unroll
    for (int nt = 0; nt < 2; ++nt)
#pragma unroll
      for (int r = 0; r < 16; ++r) o[nt][r] = 0.f;
    const u16* kp = qkvt + QKS + base + (size_t)srow * NDH + sc0;
    const u16* vp = qkvt + vbase + (size_t)srow * NSEQ + sc0;
    uint4 k0 = *(const uint4*)kp;
    uint4 k1 = *(const uint4*)(kp + 8);
    uint4 v0 = *(const uint4*)vp;
    uint4 v1 = *(const uint4*)(vp + 8);
    for (int kt = 0; kt < 32; ++kt) {
      __syncthreads();
      *(uint4*)&Ks[srow * 72 + sc0]     = k0;
      *(uint4*)&Ks[srow * 72 + sc0 + 8] = k1;
      *(uint4*)&Vt[srow * 72 + sc0]     = v0;
      *(uint4*)&Vt[srow * 72 + sc0 + 8] = v1;
      __syncthreads();
      if (kt < 31) {   // prefetch next tile during compute
        const u16* kn = kp + (size_t)(kt + 1) * 64 * NDH;
        const u16* vn = vp + (kt + 1) * 64;
        k0 = *(const uint4*)kn;
        k1 = *(const uint4*)(kn + 8);
        v0 = *(const uint4*)vn;
        v1 = *(const uint4*)(vn + 8);
      }
      // S^T: D[m=key_loc][n=q], A = K rows (my key half), B = Q (cached)
      f32x16 s;
#pragma unroll
      for (int r = 0; r < 16; ++r) s[r] = 0.f;
      __builtin_amdgcn_s_setprio(1);
#pragma unroll
      for (int c = 0; c < 4; ++c) {
        const bf16x8 ka = *(const bf16x8*)&Ks[(kh * 32 + l31) * 72 + c * 16 + hi * 8];
        s = __builtin_amdgcn_mfma_f32_32x32x16_bf16(ka, qb[c], s, 0, 0, 0);
      }
      __builtin_amdgcn_s_setprio(0);
      // softmax: p = exp2(s); per-query l: in-lane + shfl_xor(32)
      float ts = 0.f;
#pragma unroll
      for (int r = 0; r < 16; ++r) {
        s[r] = __builtin_amdgcn_exp2f(s[r]);
        ts += s[r];
      }
      ts += __shfl_xor(ts, 32);
      lacc += ts;
      // P[q=l31][key_loc]: C rows = keys (r&3)+8*(r>>2)+4*hi -> packed b64
      bf16* pr = Pw + (wq * 32 + l31) * 72;
#pragma unroll
      for (int g = 0; g < 4; ++g) {
        uint2 t = {b2pk(s[4 * g], s[4 * g + 1]), b2pk(s[4 * g + 2], s[4 * g + 3])};
        *(uint2*)&pr[g * 8 + hi * 4] = t;
      }
      // PV: A = P[m=q][k=key_loc] (wave-local, no barrier), B = Vt[n=d][k]
      __builtin_amdgcn_s_setprio(1);
#pragma unroll
      for (int c = 0; c < 2; ++c) {
        const bf16x8 pa = *(const bf16x8*)&Pw[(wq * 32 + l31) * 72 + c * 16 + hi * 8];
        const bf16x8 vb0 = *(const bf16x8*)&Vt[l31 * 72 + kh * 32 + c * 16 + hi * 8];
        const bf16x8 vb1 = *(const bf16x8*)&Vt[(32 + l31) * 72 + kh * 32 + c * 16 + hi * 8];
        o[0] = __builtin_amdgcn_mfma_f32_32x32x16_bf16(pa, vb0, o[0], 0, 0, 0);
        o[1] = __builtin_amdgcn_mfma_f32_32x32x16_bf16(pa, vb1, o[1], 0, 0, 0);
      }
      __builtin_amdgcn_s_setprio(0);
    }
    __syncthreads();   // all Vt reads done; overlay Osum on KV
    if (lane < 32) Lpart[wq * 32 + lane] = lacc;
    float* Osum = (float*)KV;   // [2][32][64]
    if (kh == 1) {
#pragma unroll
      for (int nt = 0; nt < 2; ++nt)
#pragma unroll
        for (int r = 0; r < 16; ++r) {
          const int row = (r & 3) + 8 * (r >> 2) + 4 * hi;
          Osum[(qh * 32 + row) * 64 + nt * 32 + l31] = o[nt][r];
        }
    }
    __syncthreads();
    if (kh == 0) {
      const int bb = bh >> 3, h = bh & 7;
#pragma unroll
      for (int r = 0; r < 16; ++r) {
        const int row = (r & 3) + 8 * (r >> 2) + 4 * hi;
        const float lt = Lpart[qh * 2 * 32 + row] + Lpart[(qh * 2 + 1) * 32 + row];
        const float inv = 1.f / lt;
        const int nn = q0 + qh * 32 + row;
        u16* dst = out12 + (size_t)(bb * NSEQ + nn) * 1024 + h * 128;
        dst[l31]      = f2b((o[0][r] + Osum[(qh * 32 + row) * 64 + l31]) * inv);
        dst[32 + l31] = f2b((o[1][r] + Osum[(qh * 32 + row) * 64 + 32 + l31]) * inv);
      }
    }
  } else {
    // ---- positional-decay attention (separable scans) ----
    float* sinv = (float*)usmem;              // [4][192]
    float* fb   = (float*)(usmem + 3072);     // [4][64][68]
    const int cb = bid - 512;
    const int w = tid >> 6, d = tid & 63;
    const int c  = (cb & 7) * 4 + w;          // chunk 0..31
    const int i0 = c * 64;
    const int bh = cb >> 3;
    const size_t tb = 3ull * QKS + (size_t)bh * (NSEQ * NDH);
    const float EI = 0.36787944117144233f;    // 1/e
    const float RR = 0.69220062755534635f;    // exp(-1/e)
    const float OMR = 1.f - RR;
#pragma unroll
    for (int p = 0; p < 3; ++p) {
      const int j = i0 - 64 + p * 64 + d;
      const float r1 = __expf(-(float)(j + 1) * EI);
      const float r2 = __expf(-(float)(NSEQ - j) * EI);
      sinv[w * 192 + p * 64 + d] = OMR / (1.f - r1 + RR - r2);
    }
    const u16* tp = qkvt + tb + d;
    float f = 0.f;
    if (c > 0) {
#pragma unroll 8
      for (int jj = 0; jj < 64; ++jj)
        f = RR * f + sinv[w * 192 + jj] * b2f(tp[(size_t)(i0 - 64 + jj) * NDH]);
    }
#pragma unroll 8
    for (int jj = 0; jj < 64; ++jj) {
      f = RR * f + sinv[w * 192 + 64 + jj] * b2f(tp[(size_t)(i0 + jj) * NDH]);
      fb[(w * 64 + jj) * 68 + d] = f;
    }
    float b = 0.f;
    if (c < 31) {
#pragma unroll 8
      for (int jj = 63; jj >= 0; --jj)
        b = RR * b + sinv[w * 192 + 128 + jj] * b2f(tp[(size_t)(i0 + 64 + jj) * NDH]);
    }
    const int bb = bh >> 3, h = bh & 7;
#pragma unroll 8
    for (int jj = 63; jj >= 0; --jj) {
      const float g = sinv[w * 192 + 64 + jj] * b2f(tp[(size_t)(i0 + jj) * NDH]);
      b = RR * b + g;
      out12[(size_t)(bb * NSEQ + i0 + jj) * 1024 + h * 128 + 64 + d] =
          f2b(fb[(w * 64 + jj) * 68 + d] + b - g);
    }
  }
}

// ---------------------------------------------------------------------------
// K3: out = out12[4096,1024](bf16) @ Wob[512,1024](bf16)^T + bias -> f32.
// 128x64 tiles (was 64x64: 2x MFMA per staged byte), BK=64 via 4 linear
// buffers, global_load_lds width-16 staging. Grid (32,8): per-XCD working
// set = A-stripe 1MB + B 1MB (L2-resident).
// ---------------------------------------------------------------------------
__global__ __launch_bounds__(256) void k_gemm_out(
    const u16* __restrict__ A, const u16* __restrict__ Wb,
    const float* __restrict__ bias, float* __restrict__ out) {
  __shared__ __align__(16) float smemf[6144];  // stage 24KB | epi 4x(16x36) f32
  bf16* A0e = (bf16*)smemf;          // [128][32]
  bf16* A1e = (bf16*)smemf + 4096;   // [128][32]
  bf16* B0e = (bf16*)smemf + 8192;   // [64][32]
  bf16* B1e = (bf16*)smemf + 10240;  // [64][32]
  const int tid = threadIdx.x;
  const int m0 = blockIdx.x * 128;
  const int n0 = blockIdx.y * 64;
  const int w = tid >> 6, lane = tid & 63;
  const int wy = w >> 1, wx = w & 1;
  const int quad = lane >> 4, l15 = lane & 15;
  const int srow = tid >> 2, sc8 = (tid & 3) * 8;
  const u16* ap = A  + (size_t)(m0 + srow) * 1024 + sc8;
  const u16* bp = Wb + (size_t)(n0 + srow) * 1024 + sc8;
  char* aL00 = (char*)smemf + w * 1024;            // A0 rows 0-63
  char* aL01 = (char*)smemf + 4096  + w * 1024;    // A0 rows 64-127
  char* aL10 = (char*)smemf + 8192  + w * 1024;    // A1 rows 0-63
  char* aL11 = (char*)smemf + 12288 + w * 1024;    // A1 rows 64-127
  char* bL0  = (char*)smemf + 16384 + w * 1024;    // B0
  char* bL1  = (char*)smemf + 20480 + w * 1024;    // B1
  f32x4 acc[4][2];
#pragma unroll
  for (int mt = 0; mt < 4; ++mt)
#pragma unroll
    for (int nt = 0; nt < 2; ++nt) acc[mt][nt] = (f32x4){0.f, 0.f, 0.f, 0.f};
  for (int kc = 0; kc < 1024; kc += 64) {
    __syncthreads();
    gl16(ap + kc,                  aL00);
    gl16(ap + kc + 64 * 1024,      aL01);
    gl16(ap + kc + 32,             aL10);
    gl16(ap + kc + 32 + 64 * 1024, aL11);
    gl16(bp + kc,                  bL0);
    gl16(bp + kc + 32,             bL1);
    __syncthreads();
#pragma unroll
    for (int ks = 0; ks < 2; ++ks) {
      const bf16* Ae = ks ? A1e : A0e;
      const bf16* Be = ks ? B1e : B0e;
      bf16x8 afr[4], bfr[2];
#pragma unroll
      for (int mt = 0; mt < 4; ++mt)
        afr[mt] = *(const bf16x8*)&Ae[(wy * 64 + mt * 16 + l15) * 32 + quad * 8];
#pragma unroll
      for (int nt = 0; nt < 2; ++nt)
        bfr[nt] = *(const bf16x8*)&Be[(wx * 32 + nt * 16 + l15) * 32 + quad * 8];
#pragma unroll
      for (int mt = 0; mt < 4; ++mt)
#pragma unroll
        for (int nt = 0; nt < 2; ++nt)
          acc[mt][nt] = __builtin_amdgcn_mfma_f32_16x16x32_bf16(afr[mt], bfr[nt], acc[mt][nt], 0, 0, 0);
    }
  }
  float bias_v[2];
#pragma unroll
  for (int nt = 0; nt < 2; ++nt) bias_v[nt] = bias[n0 + wx * 32 + nt * 16 + l15];
  __syncthreads();   // staging reads done; reuse smem
  float* Cw = smemf + w * 576;   // per-wave [16][36]
  const int erow = lane >> 2, ec8 = (lane & 3) * 8;
#pragma unroll
  for (int mt = 0; mt < 4; ++mt) {
#pragma unroll
    for (int nt = 0; nt < 2; ++nt)
#pragma unroll
      for (int r = 0; r < 4; ++r)
        Cw[(quad * 4 + r) * 36 + nt * 16 + l15] = acc[mt][nt][r] + bias_v[nt];
    // wave-local transpose readback: 4 lanes/row x 2 float4 = 128B/row
    const float4 v0 = *(const float4*)&Cw[erow * 36 + ec8];
    const float4 v1 = *(const float4*)&Cw[erow * 36 + ec8 + 4];
    float* op = out + (size_t)(m0 + wy * 64 + mt * 16 + erow) * 512 + n0 + wx * 32 + ec8;
    *(float4*)op       = v0;
    *(float4*)(op + 4) = v1;
  }
}

extern "C" void kernel_launch(void* const* d_in, const int* in_sizes, int n_in,
                              void* d_out, int out_size, void* d_ws, size_t ws_size,
                              hipStream_t stream) {
  (void)in_sizes; (void)n_in; (void)out_size; (void)ws_size;
  const float* x     = (const float*)d_in[0];
  const float* w_qkv = (const float*)d_in[1];
  const float* w_out = (const float*)d_in[2];
  const float* b_out = (const float*)d_in[3];
  float* out = (float*)d_out;
  u16* ws    = (u16*)d_ws;
  u16* qkvt  = ws;                               // [0, 16MB): 4 planes bf16
  u16* out12 = ws + 8ull  * 1024 * 1024;         // [16MB, 24MB)
  u16* Xb    = ws + 12ull * 1024 * 1024;         // [24MB, 28MB): 4096x512 bf16
  u16* Wqb   = ws + 14ull * 1024 * 1024;         // [28MB, 30MB): 2048x512 bf16
  u16* Wob   = ws + 15ull * 1024 * 1024;         // [30MB, 31MB): 512x1024 bf16
  k_cvt      <<<dim3(1792), 256, 0, stream>>>(x, w_qkv, w_out, Xb, Wqb, Wob);
  k_gemm_qkvt<<<dim3(32, 16), 256, 0, stream>>>(Xb, Wqb, qkvt);
  k_attn_band<<<dim3(640), 256, 0, stream>>>(qkvt, out12);
  k_gemm_out <<<dim3(32, 8), 256, 0, stream>>>(out12, Wob, b_out, out);
}